// Round 1
// baseline (4603.503 us; speedup 1.0000x reference)
//
#include <hip/hip_runtime.h>

// QuantizedSpectralConv: B=16, CIN=COUT=64, H=W=256, modes 64x64.
// Spectral slice: rows r = 96..159 (full-complex axis), cols c = 32..95 (rfft axis).
// out[b,o,h,w] = bias[o] + (2/65536) * sum_{c} Re( Z[b,o,h,c] * e^{+2pi i (32+c) w/256} )
//   Z[b,o,h,c] = sum_r Y[b,o,r,c] e^{+2pi i (96+r) h/256}
//   Y[b,o,r,c] = sum_i X[b,i,r,c] * W[i,o,r,c]        (dequantized complex weight)
//   X[b,i,r,c] = sum_h ( sum_w x[b,i,h,w] e^{-2pi i (32+c) w/256} ) e^{-2pi i (96+r) h/256}

#define HW    256
#define NMODE 64
#define NCIN  64
#define NCOUT 64
#define NB    16
#define R0    96
#define C0    32

// ---------------- trig tables (exact integer-mod angle reduction) ----------------
// C1S1[n][k]  = (cos,sin) of 2*pi*((C0+k)*n mod 256)/256   layout [w][c]
// C2S2[n][k]  = (cos,sin) of 2*pi*((R0+k)*n mod 256)/256   layout [h][r]
// C1S1T[k][n] = transpose of C1S1                          layout [c][w]
__global__ void build_tables(float2* __restrict__ C1S1,
                             float2* __restrict__ C2S2,
                             float2* __restrict__ C1S1T) {
    int idx = blockIdx.x * 256 + threadIdx.x;   // 0..16383
    int n = idx >> 6;          // 0..255
    int k = idx & 63;          // 0..63
    const float TWO_PI_OVER_256 = 0.0245436926061702596754f;
    int m1 = ((C0 + k) * n) & 255;
    float s1, c1;
    sincosf((float)m1 * TWO_PI_OVER_256, &s1, &c1);
    C1S1[n * 64 + k]   = make_float2(c1, s1);
    C1S1T[k * 256 + n] = make_float2(c1, s1);
    int m2 = ((R0 + k) * n) & 255;
    float s2, c2;
    sincosf((float)m2 * TWO_PI_OVER_256, &s2, &c2);
    C2S2[n * 64 + k] = make_float2(c2, s2);
}

// ---------------- forward: stages A+B fused, one block per (b,i) image ----------------
__global__ __launch_bounds__(256) void fwd_kernel(
        const float*  __restrict__ x,
        const float2* __restrict__ C1S1,
        const float2* __restrict__ C2S2,
        float2*       __restrict__ X) {
    int bi = blockIdx.x;                       // b*CIN + i
    const float* xim = x + (size_t)bi * (HW * HW);
    int t = threadIdx.x;
    int c = t & 63;            // col-mode per lane
    int q = t >> 6;            // wave id 0..3
    __shared__ __align__(16) float2 t1[64][64];   // T1 chunk [h_local][c], 32 KB

    float Xr[16], Xi[16];
    #pragma unroll
    for (int k = 0; k < 16; ++k) { Xr[k] = 0.f; Xi[k] = 0.f; }

    for (int ch = 0; ch < 4; ++ch) {
        // phase 1: rows h0..h0+15 (this wave's band), this thread's column c
        float t1r[16], t1i[16];
        #pragma unroll
        for (int j = 0; j < 16; ++j) { t1r[j] = 0.f; t1i[j] = 0.f; }
        int h0 = ch * 64 + q * 16;
        for (int w = 0; w < HW; w += 4) {
            float2 e0 = C1S1[(w + 0) * 64 + c];
            float2 e1 = C1S1[(w + 1) * 64 + c];
            float2 e2 = C1S1[(w + 2) * 64 + c];
            float2 e3 = C1S1[(w + 3) * 64 + c];
            #pragma unroll
            for (int j = 0; j < 16; ++j) {
                const float4 xv = *(const float4*)(xim + (h0 + j) * HW + w);
                t1r[j] += xv.x * e0.x + xv.y * e1.x + xv.z * e2.x + xv.w * e3.x;
                t1i[j] -= xv.x * e0.y + xv.y * e1.y + xv.z * e2.y + xv.w * e3.y;
            }
        }
        __syncthreads();   // previous chunk's phase 2 done reading LDS
        #pragma unroll
        for (int j = 0; j < 16; ++j) t1[q * 16 + j][c] = make_float2(t1r[j], t1i[j]);
        __syncthreads();
        // phase 2: fold this h-chunk into X[r][c]; thread owns r = q*16+k
        for (int hl = 0; hl < 64; ++hl) {
            float2 z = t1[hl][c];
            const float2* e2row = C2S2 + (ch * 64 + hl) * 64 + q * 16;
            #pragma unroll
            for (int k = 0; k < 16; ++k) {
                float2 e = e2row[k];
                Xr[k] += z.x * e.x + z.y * e.y;     // * exp(-i theta)
                Xi[k] += z.y * e.x - z.x * e.y;
            }
        }
    }
    float2* Xp = X + (size_t)bi * (NMODE * NMODE);
    #pragma unroll
    for (int k = 0; k < 16; ++k) {
        int rr = q * 16 + k;
        Xp[rr * 64 + c] = make_float2(Xr[k], Xi[k]);
    }
}

// ---------------- stage C: per-mode channel mixing with inline dequant ----------------
// grid (rr=64, otile=16); thread: c = lane, o = otile*4 + (t>>6); owns all 16 b
__global__ __launch_bounds__(256) void mix_kernel(
        const float2* __restrict__ X,
        const int*    __restrict__ q_real,
        const int*    __restrict__ q_imag,
        const float*  __restrict__ s_r, const float* __restrict__ m_r,
        const float*  __restrict__ s_i, const float* __restrict__ m_i,
        float2*       __restrict__ Y) {
    int rr = blockIdx.x;
    int ot = blockIdx.y;
    int t  = threadIdx.x;
    int c  = t & 63;
    int oq = t >> 6;
    int o  = ot * 4 + oq;
    float sr = *s_r, mr = *m_r, si = *s_i, mi = *m_i;
    __shared__ __align__(16) float2 xsh[16][64];
    float Yr[16], Yi[16];
    #pragma unroll
    for (int b = 0; b < 16; ++b) { Yr[b] = 0.f; Yi[b] = 0.f; }
    for (int i = 0; i < NCIN; ++i) {
        __syncthreads();
        #pragma unroll
        for (int l = t; l < 1024; l += 256) {
            int b = l >> 6, cc = l & 63;
            xsh[b][cc] = X[(((size_t)b * NCIN + i) * 64 + rr) * 64 + cc];
        }
        __syncthreads();
        int widx = ((i * NCOUT + o) * 64 + rr) * 64 + c;
        float wr = (float)(q_real[widx] + 127) * sr + mr;
        float wi = (float)(q_imag[widx] + 127) * si + mi;
        #pragma unroll
        for (int b = 0; b < 16; ++b) {
            float2 xv = xsh[b][c];
            Yr[b] += xv.x * wr - xv.y * wi;
            Yi[b] += xv.x * wi + xv.y * wr;
        }
    }
    #pragma unroll
    for (int b = 0; b < 16; ++b)
        Y[(((size_t)b * NCOUT + o) * 64 + rr) * 64 + c] = make_float2(Yr[b], Yi[b]);
}

// ---------------- inverse: stages D+E fused, one block per (b,o) image ----------------
__global__ __launch_bounds__(256) void inv_kernel(
        const float2* __restrict__ Y,
        const float2* __restrict__ C2S2,
        const float2* __restrict__ C1S1T,
        const int*    __restrict__ q_bias,
        const float*  __restrict__ b_s, const float* __restrict__ b_m,
        float*        __restrict__ out) {
    int bo = blockIdx.x;      // b*COUT + o
    int o  = bo & 63;
    int t  = threadIdx.x;
    __shared__ __align__(16) float2 ysh[64][64];   // whole Y[b,o] tile, 32 KB
    __shared__ __align__(16) float2 zsh[64][64];   // Z chunk [h_local][c], 32 KB
    const float2* Yp = Y + (size_t)bo * (64 * 64);
    for (int l = t; l < 4096; l += 256)
        ((float2*)ysh)[l] = Yp[l];
    float bias = ((float)q_bias[o] + 127.0f) * (*b_s) + (*b_m);
    int c = t & 63;
    int q = t >> 6;
    __syncthreads();
    for (int ch = 0; ch < 4; ++ch) {
        // phase D: Z[hl][c] for this wave's band of h
        for (int j = 0; j < 16; ++j) {
            int hl = q * 16 + j;
            const float2* e2row = C2S2 + (ch * 64 + hl) * 64;
            float zr = 0.f, zi = 0.f;
            #pragma unroll 8
            for (int r = 0; r < 64; ++r) {
                float2 e = e2row[r];
                float2 y = ysh[r][c];
                zr += y.x * e.x - y.y * e.y;   // * exp(+i theta)
                zi += y.x * e.y + y.y * e.x;
            }
            zsh[hl][c] = make_float2(zr, zi);
        }
        __syncthreads();
        // phase E: thread = w, accumulate all 64 h of this chunk in registers
        int w = t;
        float acc[64];
        #pragma unroll
        for (int hl = 0; hl < 64; ++hl) acc[hl] = 0.f;
        for (int cc = 0; cc < 64; cc += 2) {
            float2 e0 = C1S1T[(cc + 0) * 256 + w];
            float2 e1 = C1S1T[(cc + 1) * 256 + w];
            #pragma unroll 16
            for (int hl = 0; hl < 64; ++hl) {
                float4 z2 = *(const float4*)&zsh[hl][cc];
                acc[hl] += z2.x * e0.x - z2.y * e0.y + z2.z * e1.x - z2.w * e1.y;
            }
        }
        float* op = out + ((size_t)bo * HW + ch * 64) * HW + w;
        #pragma unroll
        for (int hl = 0; hl < 64; ++hl)
            op[(size_t)hl * HW] = acc[hl] * (2.0f / 65536.0f) + bias;
        __syncthreads();   // before next chunk overwrites zsh
    }
}

extern "C" void kernel_launch(void* const* d_in, const int* in_sizes, int n_in,
                              void* d_out, int out_size, void* d_ws, size_t ws_size,
                              hipStream_t stream) {
    const float* x          = (const float*)d_in[0];
    const int*   q_real     = (const int*)  d_in[1];
    const int*   q_imag     = (const int*)  d_in[2];
    const int*   q_bias     = (const int*)  d_in[3];
    const float* scale_real = (const float*)d_in[4];
    const float* min_real   = (const float*)d_in[5];
    const float* scale_imag = (const float*)d_in[6];
    const float* min_imag   = (const float*)d_in[7];
    const float* b_scale    = (const float*)d_in[8];
    const float* b_min      = (const float*)d_in[9];
    float* out = (float*)d_out;

    float* ws = (float*)d_ws;
    // workspace layout (floats): tables 98304, X 8388608, Y 8388608  (~67.5 MB)
    float2* C1S1  = (float2*)(ws);
    float2* C2S2  = (float2*)(ws + 32768);
    float2* C1S1T = (float2*)(ws + 65536);
    float2* Xws   = (float2*)(ws + 98304);
    float2* Yws   = (float2*)(ws + 98304 + 8388608);

    build_tables<<<64, 256, 0, stream>>>(C1S1, C2S2, C1S1T);
    fwd_kernel<<<NB * NCIN, 256, 0, stream>>>(x, C1S1, C2S2, Xws);
    mix_kernel<<<dim3(64, 16), 256, 0, stream>>>(Xws, q_real, q_imag,
                                                 scale_real, min_real,
                                                 scale_imag, min_imag, Yws);
    inv_kernel<<<NB * NCOUT, 256, 0, stream>>>(Yws, C2S2, C1S1T,
                                               q_bias, b_scale, b_min, out);
}

// Round 2
// 1582.349 us; speedup vs baseline: 2.9093x; 2.9093x over previous
//
#include <hip/hip_runtime.h>

// QuantizedSpectralConv: B=16, CIN=COUT=64, H=W=256, modes 64x64.
// rows r = 96..159, cols c = 32..95.
// out[b,o,h,w] = bias[o] + (2/65536) * sum_c Re( Z[b,o,h,c] e^{+2pi i (32+c) w/256} )
//   Z[b,o,h,c] = sum_r Y[b,o,r,c] e^{+2pi i (96+r) h/256}
//   Y = sum_i X * W(dequant);  X = forward spectral slice of x.

#define HW    256
#define NCIN  64
#define NCOUT 64
#define NB    16
#define R0    96
#define C0    32

typedef __bf16 bf16x8 __attribute__((ext_vector_type(8)));
typedef float  f32x4  __attribute__((ext_vector_type(4)));

__device__ __forceinline__ unsigned short f2bf(float f) {
    unsigned u = __float_as_uint(f);
    unsigned r = (u + 0x7FFFu + ((u >> 16) & 1u)) >> 16;   // RTN-even
    return (unsigned short)r;
}
__device__ __forceinline__ bf16x8 ld_frag_g(const unsigned short* p) {
    return __builtin_bit_cast(bf16x8, *(const uint4*)p);
}

// ---------------- trig tables ----------------
// C1S1[w][c] = (cos,sin) 2pi((C0+c)w mod 256)/256 ;  C2S2[h][r] = same with R0.
__global__ void build_tables(float2* __restrict__ C1S1,
                             float2* __restrict__ C2S2) {
    int idx = blockIdx.x * 256 + threadIdx.x;   // 0..16383
    int n = idx >> 6;
    int k = idx & 63;
    const float TPO = 0.0245436926061702596754f;
    int m1 = ((C0 + k) * n) & 255;
    float s1, c1; sincosf((float)m1 * TPO, &s1, &c1);
    C1S1[n * 64 + k] = make_float2(c1, s1);
    int m2 = ((R0 + k) * n) & 255;
    float s2, c2; sincosf((float)m2 * TPO, &s2, &c2);
    C2S2[n * 64 + k] = make_float2(c2, s2);
}

// bf16 MFMA operand tables for the inverse stage:
// A1tab[h][k], k<64: cos(2pi(R0+k)h/256), k>=64: sin(2pi(R0+k-64)h/256)   [256][128]
// B2T[w][k],  k<64: cos(2pi(C0+k)w/256), k>=64: -sin(2pi(C0+k-64)w/256)   [256][128]
__global__ void build_tables2(unsigned short* __restrict__ A1tab,
                              unsigned short* __restrict__ B2T) {
    int idx = blockIdx.x * 256 + threadIdx.x;   // 0..32767
    int h = idx >> 7;
    int k = idx & 127;
    int kk = k & 63;
    const float TPO = 0.0245436926061702596754f;
    float s, c;
    int m1 = (((R0 + kk) * h) & 255);
    sincosf((float)m1 * TPO, &s, &c);
    A1tab[idx] = f2bf(k < 64 ? c : s);
    int m2 = (((C0 + kk) * h) & 255);
    sincosf((float)m2 * TPO, &s, &c);
    B2T[idx] = f2bf(k < 64 ? c : -s);
}

// ---------------- forward: stages A+B fused (unchanged) ----------------
__global__ __launch_bounds__(256) void fwd_kernel(
        const float*  __restrict__ x,
        const float2* __restrict__ C1S1,
        const float2* __restrict__ C2S2,
        float2*       __restrict__ X) {
    int bi = blockIdx.x;
    const float* xim = x + (size_t)bi * (HW * HW);
    int t = threadIdx.x;
    int c = t & 63;
    int q = t >> 6;
    __shared__ __align__(16) float2 t1[64][64];

    float Xr[16], Xi[16];
    #pragma unroll
    for (int k = 0; k < 16; ++k) { Xr[k] = 0.f; Xi[k] = 0.f; }

    for (int ch = 0; ch < 4; ++ch) {
        float t1r[16], t1i[16];
        #pragma unroll
        for (int j = 0; j < 16; ++j) { t1r[j] = 0.f; t1i[j] = 0.f; }
        int h0 = ch * 64 + q * 16;
        for (int w = 0; w < HW; w += 4) {
            float2 e0 = C1S1[(w + 0) * 64 + c];
            float2 e1 = C1S1[(w + 1) * 64 + c];
            float2 e2 = C1S1[(w + 2) * 64 + c];
            float2 e3 = C1S1[(w + 3) * 64 + c];
            #pragma unroll
            for (int j = 0; j < 16; ++j) {
                const float4 xv = *(const float4*)(xim + (h0 + j) * HW + w);
                t1r[j] += xv.x * e0.x + xv.y * e1.x + xv.z * e2.x + xv.w * e3.x;
                t1i[j] -= xv.x * e0.y + xv.y * e1.y + xv.z * e2.y + xv.w * e3.y;
            }
        }
        __syncthreads();
        #pragma unroll
        for (int j = 0; j < 16; ++j) t1[q * 16 + j][c] = make_float2(t1r[j], t1i[j]);
        __syncthreads();
        for (int hl = 0; hl < 64; ++hl) {
            float2 z = t1[hl][c];
            const float2* e2row = C2S2 + (ch * 64 + hl) * 64 + q * 16;
            #pragma unroll
            for (int k = 0; k < 16; ++k) {
                float2 e = e2row[k];
                Xr[k] += z.x * e.x + z.y * e.y;
                Xi[k] += z.y * e.x - z.x * e.y;
            }
        }
    }
    float2* Xp = X + (size_t)bi * (64 * 64);
    #pragma unroll
    for (int k = 0; k < 16; ++k) {
        int rr = q * 16 + k;
        Xp[rr * 64 + c] = make_float2(Xr[k], Xi[k]);
    }
}

// ---------------- stage C: channel mixing (unchanged) ----------------
__global__ __launch_bounds__(256) void mix_kernel(
        const float2* __restrict__ X,
        const int*    __restrict__ q_real,
        const int*    __restrict__ q_imag,
        const float*  __restrict__ s_r, const float* __restrict__ m_r,
        const float*  __restrict__ s_i, const float* __restrict__ m_i,
        float2*       __restrict__ Y) {
    int rr = blockIdx.x;
    int ot = blockIdx.y;
    int t  = threadIdx.x;
    int c  = t & 63;
    int oq = t >> 6;
    int o  = ot * 4 + oq;
    float sr = *s_r, mr = *m_r, si = *s_i, mi = *m_i;
    __shared__ __align__(16) float2 xsh[16][64];
    float Yr[16], Yi[16];
    #pragma unroll
    for (int b = 0; b < 16; ++b) { Yr[b] = 0.f; Yi[b] = 0.f; }
    for (int i = 0; i < NCIN; ++i) {
        __syncthreads();
        #pragma unroll
        for (int l = t; l < 1024; l += 256) {
            int b = l >> 6, cc = l & 63;
            xsh[b][cc] = X[(((size_t)b * NCIN + i) * 64 + rr) * 64 + cc];
        }
        __syncthreads();
        int widx = ((i * NCOUT + o) * 64 + rr) * 64 + c;
        float wr = (float)(q_real[widx] + 127) * sr + mr;
        float wi = (float)(q_imag[widx] + 127) * si + mi;
        #pragma unroll
        for (int b = 0; b < 16; ++b) {
            float2 xv = xsh[b][c];
            Yr[b] += xv.x * wr - xv.y * wi;
            Yi[b] += xv.x * wi + xv.y * wr;
        }
    }
    #pragma unroll
    for (int b = 0; b < 16; ++b)
        Y[(((size_t)b * NCOUT + o) * 64 + rr) * 64 + c] = make_float2(Yr[b], Yi[b]);
}

// ---------------- inverse: D+E as two bf16 MFMA GEMMs per (b,o) image ----------------
// GEMM1: Z[256][128] = A1[256][128] * B1[128][128],  B1 = [[Yr, Yi], [-Yi, Yr]]
// GEMM2: out[256][256] = Z[256][128] * B2[128][256]
// LDS union (64KB ushort[32768]): B1T [128][128] in first half, then Zsh [256][128].
// XOR swizzle on both: element k' = k ^ ((row&7)<<3)  -> conflict-free ds_read_b128.
__global__ __launch_bounds__(256, 2) void inv_mfma(
        const float2*        __restrict__ Y,
        const unsigned short* __restrict__ A1tab,
        const unsigned short* __restrict__ B2T,
        const int*           __restrict__ q_bias,
        const float* __restrict__ b_s, const float* __restrict__ b_m,
        float*               __restrict__ out) {
    __shared__ __align__(16) unsigned short smem[32768];
    int bo   = blockIdx.x;
    int t    = threadIdx.x;
    int lane = t & 63;
    int wv   = t >> 6;
    int g    = lane >> 4;       // k-group 0..3
    int lr   = lane & 15;       // row/col within fragment
    float bias = ((float)q_bias[bo & 63] + 127.0f) * (*b_s) + (*b_m);

    // ---- build B1T (bf16, swizzled): B1T[n][k] ----
    const float2* Yp = Y + (size_t)bo * 4096;
    for (int l = t; l < 4096; l += 256) {
        int r = l >> 6, c = l & 63;
        float2 y = Yp[l];
        unsigned short yr  = f2bf(y.x);
        unsigned short yi  = f2bf(y.y);
        unsigned short nyi = f2bf(-y.y);
        int sw = (c & 7) << 3;   // (64+c)&7 == c&7
        smem[c * 128        + ((r)      ^ sw)] = yr;    // Zr part, k<64:  Yr
        smem[c * 128        + ((64 + r) ^ sw)] = nyi;   // Zr part, k>=64: -Yi
        smem[(64 + c) * 128 + ((r)      ^ sw)] = yi;    // Zi part, k<64:  Yi
        smem[(64 + c) * 128 + ((64 + r) ^ sw)] = yr;    // Zi part, k>=64: Yr
    }
    __syncthreads();

    // ---- GEMM1: wave computes Z rows wv*64 .. wv*64+63 ----
    f32x4 acc[4][8];
    #pragma unroll
    for (int mf = 0; mf < 4; ++mf)
        #pragma unroll
        for (int nf = 0; nf < 8; ++nf)
            acc[mf][nf] = (f32x4)0.0f;

    #pragma unroll
    for (int ks = 0; ks < 4; ++ks) {
        int k0 = ks * 32 + g * 8;
        bf16x8 a[4], b[8];
        #pragma unroll
        for (int mf = 0; mf < 4; ++mf) {
            int h = wv * 64 + mf * 16 + lr;
            a[mf] = ld_frag_g(A1tab + h * 128 + k0);
        }
        #pragma unroll
        for (int nf = 0; nf < 8; ++nf) {
            int n = nf * 16 + lr;
            b[nf] = ld_frag_g(&smem[n * 128 + (k0 ^ ((n & 7) << 3))]);
        }
        #pragma unroll
        for (int mf = 0; mf < 4; ++mf)
            #pragma unroll
            for (int nf = 0; nf < 8; ++nf)
                acc[mf][nf] = __builtin_amdgcn_mfma_f32_16x16x32_bf16(
                                  a[mf], b[nf], acc[mf][nf], 0, 0, 0);
    }
    __syncthreads();   // everyone done reading B1T

    // ---- store Z -> smem (bf16, swizzled). C/D layout: col=lane&15, row=(lane>>4)*4+reg
    #pragma unroll
    for (int mf = 0; mf < 4; ++mf)
        #pragma unroll
        for (int nf = 0; nf < 8; ++nf)
            #pragma unroll
            for (int rg = 0; rg < 4; ++rg) {
                int h = wv * 64 + mf * 16 + g * 4 + rg;
                int k = nf * 16 + lr;
                smem[h * 128 + (k ^ ((h & 7) << 3))] = f2bf(acc[mf][nf][rg]);
            }
    __syncthreads();

    // ---- GEMM2: out rows wv*64 .. +63, all 256 w in two halves ----
    const float scale = 2.0f / 65536.0f;
    float* outp = out + (size_t)bo * 65536;
    #pragma unroll
    for (int nh = 0; nh < 2; ++nh) {
        f32x4 acc2[4][8];
        #pragma unroll
        for (int mf = 0; mf < 4; ++mf)
            #pragma unroll
            for (int nf = 0; nf < 8; ++nf)
                acc2[mf][nf] = (f32x4)0.0f;

        #pragma unroll
        for (int ks = 0; ks < 4; ++ks) {
            int k0 = ks * 32 + g * 8;
            bf16x8 a[4], b[8];
            #pragma unroll
            for (int mf = 0; mf < 4; ++mf) {
                int h = wv * 64 + mf * 16 + lr;
                a[mf] = ld_frag_g(&smem[h * 128 + (k0 ^ ((h & 7) << 3))]);
            }
            #pragma unroll
            for (int nf = 0; nf < 8; ++nf) {
                int w = nh * 128 + nf * 16 + lr;
                b[nf] = ld_frag_g(B2T + w * 128 + k0);
            }
            #pragma unroll
            for (int mf = 0; mf < 4; ++mf)
                #pragma unroll
                for (int nf = 0; nf < 8; ++nf)
                    acc2[mf][nf] = __builtin_amdgcn_mfma_f32_16x16x32_bf16(
                                       a[mf], b[nf], acc2[mf][nf], 0, 0, 0);
        }
        #pragma unroll
        for (int mf = 0; mf < 4; ++mf)
            #pragma unroll
            for (int rg = 0; rg < 4; ++rg) {
                int h = wv * 64 + mf * 16 + g * 4 + rg;
                float* row = outp + h * 256 + nh * 128 + lr;
                #pragma unroll
                for (int nf = 0; nf < 8; ++nf)
                    row[nf * 16] = acc2[mf][nf][rg] * scale + bias;
            }
    }
}

extern "C" void kernel_launch(void* const* d_in, const int* in_sizes, int n_in,
                              void* d_out, int out_size, void* d_ws, size_t ws_size,
                              hipStream_t stream) {
    const float* x          = (const float*)d_in[0];
    const int*   q_real     = (const int*)  d_in[1];
    const int*   q_imag     = (const int*)  d_in[2];
    const int*   q_bias     = (const int*)  d_in[3];
    const float* scale_real = (const float*)d_in[4];
    const float* min_real   = (const float*)d_in[5];
    const float* scale_imag = (const float*)d_in[6];
    const float* min_imag   = (const float*)d_in[7];
    const float* b_scale    = (const float*)d_in[8];
    const float* b_min      = (const float*)d_in[9];
    float* out = (float*)d_out;

    float* ws = (float*)d_ws;
    // workspace (float units): C1S1 [0,32768), C2S2 [32768,65536),
    // A1tab bf16 [65536,81920), B2T bf16 [81920,98304), X [98304,+8388608), Y after.
    float2*         C1S1  = (float2*)(ws);
    float2*         C2S2  = (float2*)(ws + 32768);
    unsigned short* A1tab = (unsigned short*)(ws + 65536);
    unsigned short* B2T   = (unsigned short*)(ws + 81920);
    float2*         Xws   = (float2*)(ws + 98304);
    float2*         Yws   = (float2*)(ws + 98304 + 8388608);

    build_tables<<<64, 256, 0, stream>>>(C1S1, C2S2);
    build_tables2<<<128, 256, 0, stream>>>(A1tab, B2T);
    fwd_kernel<<<NB * NCIN, 256, 0, stream>>>(x, C1S1, C2S2, Xws);
    mix_kernel<<<dim3(64, 16), 256, 0, stream>>>(Xws, q_real, q_imag,
                                                 scale_real, min_real,
                                                 scale_imag, min_imag, Yws);
    inv_mfma<<<NB * NCOUT, 256, 0, stream>>>(Yws, A1tab, B2T,
                                             q_bias, b_scale, b_min, out);
}

// Round 3
// 357.996 us; speedup vs baseline: 12.8591x; 4.4200x over previous
//
#include <hip/hip_runtime.h>

// QuantizedSpectralConv: B=16, CIN=COUT=64, H=W=256, modes 64x64.
// rows r = 96..159 (h-axis modes), cols c = 32..95 (rfft w-axis modes).
// fwd:  T1[h][c] = sum_w x[h][w] e^{-2pi i (C0+c)w/256}
//       X[r][c]  = sum_h T1[h][c] e^{-2pi i (R0+r)h/256}
// mix:  Y[b,o,r,c] = sum_i X[b,i,r,c] * W[i,o,r,c]   (dequant)
// inv:  Z[h][c] = sum_r Y[r][c] e^{+2pi i (R0+r)h/256}
//       out[h][w] = bias + (2/65536) sum_c Re(Z[h][c] e^{+2pi i (C0+c)w/256})

#define HW    256
#define NCIN  64
#define NCOUT 64
#define NB    16
#define R0    96
#define C0    32

typedef __bf16 bf16x8 __attribute__((ext_vector_type(8)));
typedef float  f32x4  __attribute__((ext_vector_type(4)));

__device__ __forceinline__ unsigned short f2bf(float f) {
    unsigned u = __float_as_uint(f);
    unsigned r = (u + 0x7FFFu + ((u >> 16) & 1u)) >> 16;   // RTN-even
    return (unsigned short)r;
}
__device__ __forceinline__ bf16x8 ld_frag_g(const unsigned short* p) {
    return __builtin_bit_cast(bf16x8, *(const uint4*)p);
}
__device__ __forceinline__ unsigned pk2(float a, float b) {
    return (unsigned)f2bf(a) | ((unsigned)f2bf(b) << 16);
}

// ---------------- inverse-stage tables ----------------
// A1tab[h][k]: k<64 cos(2pi(R0+k)h/256), k>=64 sin(...)          [256][128]
// B2T[w][k]:   k<64 cos(2pi(C0+k)w/256), k>=64 -sin(...)         [256][128]
__global__ void build_tables2(unsigned short* __restrict__ A1tab,
                              unsigned short* __restrict__ B2T) {
    int idx = blockIdx.x * 256 + threadIdx.x;   // 0..32767
    int h = idx >> 7;
    int k = idx & 127;
    int kk = k & 63;
    const float TPO = 0.0245436926061702596754f;
    float s, c;
    int m1 = (((R0 + kk) * h) & 255);
    sincosf((float)m1 * TPO, &s, &c);
    A1tab[idx] = f2bf(k < 64 ? c : s);
    int m2 = (((C0 + kk) * h) & 255);
    sincosf((float)m2 * TPO, &s, &c);
    B2T[idx] = f2bf(k < 64 ? c : -s);
}

// ---------------- forward-stage tables ----------------
// B1fT[c][w] [128][256]: c<64 cos(2pi(C0+c)w/256), c>=64 -sin(2pi(C0+c-64)w/256)
// A2f[m][k]  [128][512]: r=m&63, h=k&255, th=2pi(R0+r)h/256
//   m<64 (Xr): k<256 cos, k>=256 sin ;  m>=64 (Xi): k<256 -sin, k>=256 cos
__global__ void build_fwd_tables(unsigned short* __restrict__ B1fT,
                                 unsigned short* __restrict__ A2f) {
    int idx = blockIdx.x * 256 + threadIdx.x;   // 0..98303
    const float TPO = 0.0245436926061702596754f;
    float s, c;
    if (idx < 32768) {
        int cc = idx >> 8, w = idx & 255;
        int m = (((C0 + (cc & 63)) * w) & 255);
        sincosf((float)m * TPO, &s, &c);
        B1fT[idx] = f2bf(cc < 64 ? c : -s);
    } else {
        int j = idx - 32768;
        int mr = j >> 9, k = j & 511;
        int m = (((R0 + (mr & 63)) * (k & 255)) & 255);
        sincosf((float)m * TPO, &s, &c);
        float v = (mr < 64) ? ((k < 256) ? c : s)
                            : ((k < 256) ? -s : c);
        A2f[j] = f2bf(v);
    }
}

// ---------------- forward: two bf16 MFMA GEMMs per (b,i) image ----------------
// GEMM-A: T1cat[256h][128col] = x[256][256] * B1f ; col<64 -> T1r[.][col], col>=64 -> T1i
// GEMM-B: Xcat[128][64c] = A2f[128][512] * Bop[512][64c] ; Bop[k<256=h][c]=T1r, [256+h][c]=T1i
// smem union: phase A x-chunk bf16 [256][64] (32KB) -> Bop stored as [c][512k] (64KB)
__global__ __launch_bounds__(256) void fwd_mfma(
        const float*          __restrict__ x,
        const unsigned short* __restrict__ B1fT,
        const unsigned short* __restrict__ A2f,
        float*                __restrict__ Xout) {
    __shared__ __align__(16) unsigned short smem[32768];   // 64 KB
    int bi = blockIdx.x;
    const float* xim = x + (size_t)bi * 65536;
    int t = threadIdx.x, lane = t & 63, wv = t >> 6;
    int g = lane >> 4, lr = lane & 15;

    f32x4 acc[4][8];
    #pragma unroll
    for (int mf = 0; mf < 4; ++mf)
        #pragma unroll
        for (int nf = 0; nf < 8; ++nf) acc[mf][nf] = (f32x4)0.0f;

    for (int ch = 0; ch < 4; ++ch) {
        __syncthreads();   // prior chunk's LDS reads done
        // stage x[256][ch*64 .. +63] -> bf16 swizzled xch[h][64]
        int hb = t >> 3, grp = t & 7;
        #pragma unroll
        for (int j = 0; j < 8; ++j) {
            int h = hb + j * 32;
            const float* rp = xim + h * 256 + ch * 64 + grp * 8;
            const float4 v0 = *(const float4*)(rp);
            const float4 v1 = *(const float4*)(rp + 4);
            uint4 pk;
            pk.x = pk2(v0.x, v0.y); pk.y = pk2(v0.z, v0.w);
            pk.z = pk2(v1.x, v1.y); pk.w = pk2(v1.z, v1.w);
            int wl = (grp * 8) ^ ((h & 7) << 3);
            *(uint4*)&smem[h * 64 + wl] = pk;
        }
        __syncthreads();
        #pragma unroll
        for (int ks = 0; ks < 2; ++ks) {
            int k0 = ks * 32 + g * 8;
            bf16x8 a[4], b[8];
            #pragma unroll
            for (int mf = 0; mf < 4; ++mf) {
                int h = wv * 64 + mf * 16 + lr;
                a[mf] = __builtin_bit_cast(bf16x8,
                          *(const uint4*)&smem[h * 64 + (k0 ^ ((h & 7) << 3))]);
            }
            #pragma unroll
            for (int nf = 0; nf < 8; ++nf) {
                int n = nf * 16 + lr;
                b[nf] = ld_frag_g(B1fT + n * 256 + ch * 64 + k0);
            }
            #pragma unroll
            for (int mf = 0; mf < 4; ++mf)
                #pragma unroll
                for (int nf = 0; nf < 8; ++nf)
                    acc[mf][nf] = __builtin_amdgcn_mfma_f32_16x16x32_bf16(
                                      a[mf], b[nf], acc[mf][nf], 0, 0, 0);
        }
    }
    __syncthreads();   // all xch reads done; smem becomes Bop[64][512]

    // T1 -> Bop (bf16, swizzled); C/D: row h = wv*64+mf*16+g*4+rg, col = nf*16+lr
    #pragma unroll
    for (int mf = 0; mf < 4; ++mf)
        #pragma unroll
        for (int nf = 0; nf < 8; ++nf) {
            int cl  = nf * 16 + lr;
            int col = cl & 63;
            int h0  = wv * 64 + mf * 16 + g * 4;
            int kk0 = (cl < 64) ? h0 : (256 + h0);
            uint2 pk;
            pk.x = pk2(acc[mf][nf][0], acc[mf][nf][1]);
            pk.y = pk2(acc[mf][nf][2], acc[mf][nf][3]);
            *(uint2*)&smem[col * 512 + (kk0 ^ ((col & 7) << 3))] = pk;
        }
    __syncthreads();

    // GEMM-B: rows wv*32..+31 of Xcat
    f32x4 acc2[2][4];
    #pragma unroll
    for (int mf = 0; mf < 2; ++mf)
        #pragma unroll
        for (int nf = 0; nf < 4; ++nf) acc2[mf][nf] = (f32x4)0.0f;
    #pragma unroll
    for (int ks = 0; ks < 16; ++ks) {
        int k0 = ks * 32 + g * 8;
        bf16x8 a2[2], b2[4];
        #pragma unroll
        for (int mf = 0; mf < 2; ++mf) {
            int m = wv * 32 + mf * 16 + lr;
            a2[mf] = ld_frag_g(A2f + m * 512 + k0);
        }
        #pragma unroll
        for (int nf = 0; nf < 4; ++nf) {
            int c = nf * 16 + lr;
            b2[nf] = __builtin_bit_cast(bf16x8,
                       *(const uint4*)&smem[c * 512 + (k0 ^ ((c & 7) << 3))]);
        }
        #pragma unroll
        for (int mf = 0; mf < 2; ++mf)
            #pragma unroll
            for (int nf = 0; nf < 4; ++nf)
                acc2[mf][nf] = __builtin_amdgcn_mfma_f32_16x16x32_bf16(
                                   a2[mf], b2[nf], acc2[mf][nf], 0, 0, 0);
    }
    // X planes: [bi][p][r][c], p=0 real, p=1 imag (fp32)
    float* Xp = Xout + (size_t)bi * 8192;
    #pragma unroll
    for (int mf = 0; mf < 2; ++mf)
        #pragma unroll
        for (int nf = 0; nf < 4; ++nf)
            #pragma unroll
            for (int rg = 0; rg < 4; ++rg) {
                int m = wv * 32 + mf * 16 + g * 4 + rg;
                int c = nf * 16 + lr;
                Xp[(m >> 6) * 4096 + (m & 63) * 64 + c] = acc2[mf][nf][rg];
            }
}

// ---------------- stage C: channel mixing (X now split planes) ----------------
__global__ __launch_bounds__(256) void mix_kernel(
        const float* __restrict__ X,
        const int*   __restrict__ q_real,
        const int*   __restrict__ q_imag,
        const float* __restrict__ s_r, const float* __restrict__ m_r,
        const float* __restrict__ s_i, const float* __restrict__ m_i,
        float2*      __restrict__ Y) {
    int rr = blockIdx.x;
    int ot = blockIdx.y;
    int t  = threadIdx.x;
    int c  = t & 63;
    int oq = t >> 6;
    int o  = ot * 4 + oq;
    float sr = *s_r, mr = *m_r, si = *s_i, mi = *m_i;
    __shared__ __align__(16) float2 xsh[16][64];
    float Yr[16], Yi[16];
    #pragma unroll
    for (int b = 0; b < 16; ++b) { Yr[b] = 0.f; Yi[b] = 0.f; }
    for (int i = 0; i < NCIN; ++i) {
        __syncthreads();
        #pragma unroll
        for (int l = t; l < 1024; l += 256) {
            int b = l >> 6, cc = l & 63;
            size_t base = (size_t)(b * NCIN + i) * 8192 + rr * 64 + cc;
            xsh[b][cc] = make_float2(X[base], X[base + 4096]);
        }
        __syncthreads();
        int widx = ((i * NCOUT + o) * 64 + rr) * 64 + c;
        float wr = (float)(q_real[widx] + 127) * sr + mr;
        float wi = (float)(q_imag[widx] + 127) * si + mi;
        #pragma unroll
        for (int b = 0; b < 16; ++b) {
            float2 xv = xsh[b][c];
            Yr[b] += xv.x * wr - xv.y * wi;
            Yi[b] += xv.x * wi + xv.y * wr;
        }
    }
    #pragma unroll
    for (int b = 0; b < 16; ++b)
        Y[(((size_t)b * NCOUT + o) * 64 + rr) * 64 + c] = make_float2(Yr[b], Yi[b]);
}

// ---------------- inverse: two bf16 MFMA GEMMs per (b,o) image ----------------
__global__ __launch_bounds__(256, 2) void inv_mfma(
        const float2*         __restrict__ Y,
        const unsigned short* __restrict__ A1tab,
        const unsigned short* __restrict__ B2T,
        const int*            __restrict__ q_bias,
        const float* __restrict__ b_s, const float* __restrict__ b_m,
        float*                __restrict__ out) {
    __shared__ __align__(16) unsigned short smem[32768];
    int bo   = blockIdx.x;
    int t    = threadIdx.x;
    int lane = t & 63;
    int wv   = t >> 6;
    int g    = lane >> 4;
    int lr   = lane & 15;
    float bias = ((float)q_bias[bo & 63] + 127.0f) * (*b_s) + (*b_m);

    const float2* Yp = Y + (size_t)bo * 4096;
    for (int l = t; l < 4096; l += 256) {
        int r = l >> 6, c = l & 63;
        float2 y = Yp[l];
        unsigned short yr  = f2bf(y.x);
        unsigned short yi  = f2bf(y.y);
        unsigned short nyi = f2bf(-y.y);
        int sw = (c & 7) << 3;
        smem[c * 128        + ((r)      ^ sw)] = yr;
        smem[c * 128        + ((64 + r) ^ sw)] = nyi;
        smem[(64 + c) * 128 + ((r)      ^ sw)] = yi;
        smem[(64 + c) * 128 + ((64 + r) ^ sw)] = yr;
    }
    __syncthreads();

    f32x4 acc[4][8];
    #pragma unroll
    for (int mf = 0; mf < 4; ++mf)
        #pragma unroll
        for (int nf = 0; nf < 8; ++nf) acc[mf][nf] = (f32x4)0.0f;

    #pragma unroll
    for (int ks = 0; ks < 4; ++ks) {
        int k0 = ks * 32 + g * 8;
        bf16x8 a[4], b[8];
        #pragma unroll
        for (int mf = 0; mf < 4; ++mf) {
            int h = wv * 64 + mf * 16 + lr;
            a[mf] = ld_frag_g(A1tab + h * 128 + k0);
        }
        #pragma unroll
        for (int nf = 0; nf < 8; ++nf) {
            int n = nf * 16 + lr;
            b[nf] = ld_frag_g(&smem[n * 128 + (k0 ^ ((n & 7) << 3))]);
        }
        #pragma unroll
        for (int mf = 0; mf < 4; ++mf)
            #pragma unroll
            for (int nf = 0; nf < 8; ++nf)
                acc[mf][nf] = __builtin_amdgcn_mfma_f32_16x16x32_bf16(
                                  a[mf], b[nf], acc[mf][nf], 0, 0, 0);
    }
    __syncthreads();

    #pragma unroll
    for (int mf = 0; mf < 4; ++mf)
        #pragma unroll
        for (int nf = 0; nf < 8; ++nf)
            #pragma unroll
            for (int rg = 0; rg < 4; ++rg) {
                int h = wv * 64 + mf * 16 + g * 4 + rg;
                int k = nf * 16 + lr;
                smem[h * 128 + (k ^ ((h & 7) << 3))] = f2bf(acc[mf][nf][rg]);
            }
    __syncthreads();

    const float scale = 2.0f / 65536.0f;
    float* outp = out + (size_t)bo * 65536;
    #pragma unroll
    for (int nh = 0; nh < 2; ++nh) {
        f32x4 acc2[4][8];
        #pragma unroll
        for (int mf = 0; mf < 4; ++mf)
            #pragma unroll
            for (int nf = 0; nf < 8; ++nf) acc2[mf][nf] = (f32x4)0.0f;

        #pragma unroll
        for (int ks = 0; ks < 4; ++ks) {
            int k0 = ks * 32 + g * 8;
            bf16x8 a[4], b[8];
            #pragma unroll
            for (int mf = 0; mf < 4; ++mf) {
                int h = wv * 64 + mf * 16 + lr;
                a[mf] = ld_frag_g(&smem[h * 128 + (k0 ^ ((h & 7) << 3))]);
            }
            #pragma unroll
            for (int nf = 0; nf < 8; ++nf) {
                int w = nh * 128 + nf * 16 + lr;
                b[nf] = ld_frag_g(B2T + w * 128 + k0);
            }
            #pragma unroll
            for (int mf = 0; mf < 4; ++mf)
                #pragma unroll
                for (int nf = 0; nf < 8; ++nf)
                    acc2[mf][nf] = __builtin_amdgcn_mfma_f32_16x16x32_bf16(
                                       a[mf], b[nf], acc2[mf][nf], 0, 0, 0);
        }
        #pragma unroll
        for (int mf = 0; mf < 4; ++mf)
            #pragma unroll
            for (int rg = 0; rg < 4; ++rg) {
                int h = wv * 64 + mf * 16 + g * 4 + rg;
                float* row = outp + h * 256 + nh * 128 + lr;
                #pragma unroll
                for (int nf = 0; nf < 8; ++nf)
                    row[nf * 16] = acc2[mf][nf][rg] * scale + bias;
            }
    }
}

extern "C" void kernel_launch(void* const* d_in, const int* in_sizes, int n_in,
                              void* d_out, int out_size, void* d_ws, size_t ws_size,
                              hipStream_t stream) {
    const float* x          = (const float*)d_in[0];
    const int*   q_real     = (const int*)  d_in[1];
    const int*   q_imag     = (const int*)  d_in[2];
    const int*   q_bias     = (const int*)  d_in[3];
    const float* scale_real = (const float*)d_in[4];
    const float* min_real   = (const float*)d_in[5];
    const float* scale_imag = (const float*)d_in[6];
    const float* min_imag   = (const float*)d_in[7];
    const float* b_scale    = (const float*)d_in[8];
    const float* b_min      = (const float*)d_in[9];
    float* out = (float*)d_out;

    float* ws = (float*)d_ws;
    // float-unit offsets:
    // A1tab bf16 [0,16384) ; B2T bf16 [16384,32768) ; B1fT bf16 [32768,49152)
    // A2f bf16 [49152,81920) ; X fp32 planes [81920, +8388608) ; Y float2 after.
    unsigned short* A1tab = (unsigned short*)(ws);
    unsigned short* B2T   = (unsigned short*)(ws + 16384);
    unsigned short* B1fT  = (unsigned short*)(ws + 32768);
    unsigned short* A2f   = (unsigned short*)(ws + 49152);
    float*          Xws   = (float*) (ws + 81920);
    float2*         Yws   = (float2*)(ws + 81920 + 8388608);

    build_tables2<<<128, 256, 0, stream>>>(A1tab, B2T);
    build_fwd_tables<<<384, 256, 0, stream>>>(B1fT, A2f);
    fwd_mfma<<<NB * NCIN, 256, 0, stream>>>(x, B1fT, A2f, Xws);
    mix_kernel<<<dim3(64, 16), 256, 0, stream>>>(Xws, q_real, q_imag,
                                                 scale_real, min_real,
                                                 scale_imag, min_imag, Yws);
    inv_mfma<<<NB * NCOUT, 256, 0, stream>>>(Yws, A1tab, B2T,
                                             q_bias, b_scale, b_min, out);
}